// Round 4
// baseline (254.998 us; speedup 1.0000x reference)
//
#include <hip/hip_runtime.h>

typedef __attribute__((ext_vector_type(8))) short short8;
typedef __attribute__((ext_vector_type(4))) float f32x4;
typedef unsigned short ushort_t;
typedef unsigned int uint_t;

#define SEQ 4096
#define NB 4
#define EMB 1024
#define HD 128

__device__ __forceinline__ ushort_t f2bf(float f) {
  uint_t u = __float_as_uint(f);
  u += 0x7fffu + ((u >> 16) & 1u);
  return (ushort_t)(u >> 16);
}
__device__ __forceinline__ float bf2f(ushort_t h) {
  return __uint_as_float(((uint_t)h) << 16);
}
__device__ __forceinline__ short8 pack8(float4 u, float4 v) {
  short8 r;
  r[0] = (short)f2bf(u.x); r[1] = (short)f2bf(u.y);
  r[2] = (short)f2bf(u.z); r[3] = (short)f2bf(u.w);
  r[4] = (short)f2bf(v.x); r[5] = (short)f2bf(v.y);
  r[6] = (short)f2bf(v.z); r[7] = (short)f2bf(v.w);
  return r;
}

// -------------------- Kernel 0: weight transpose+convert --------------------
// k-fastest mapping: coalesced WRITES to Wt; scattered reads served by L2 (W=1.5MB).
__global__ __launch_bounds__(256) void wt_prep(const float* __restrict__ Wq,
                                               const float* __restrict__ Wk,
                                               const float* __restrict__ Wv,
                                               ushort_t* __restrict__ Wt) {
  int idx = blockIdx.x * 256 + threadIdx.x;  // 3*131072 threads
  int o = idx >> 17;
  int r = idx & 131071;
  int n = r >> 10;
  int k = r & 1023;
  const float* W = (o == 0) ? Wq : ((o == 1) ? Wk : Wv);
  Wt[o * 131072 + n * 1024 + k] = f2bf(W[k * 128 + n]);
}

// -------------------- Kernel 1: fused QKV projection, no LDS --------------------
// 512 blocks x 512 thr (8 waves). Block = 32 x-rows (shared by all waves via L1/L2);
// wave w covers col-groups w*3..w*3+2 of 24 (q:0-7, k:8-15, v:16-23).
// B-frags straight from L2-resident Wt; zero barriers -> deep pipelining.
// Conversion fp32->bf16 via pure-C f2bf (known-good; cvt_pk asm suspected in r3 NaN).
__global__ __launch_bounds__(512, 4) void proj(const float* __restrict__ x,
                                               const ushort_t* __restrict__ Wt,
                                               ushort_t* __restrict__ qb,
                                               ushort_t* __restrict__ kb,
                                               ushort_t* __restrict__ vt) {
  int m0 = blockIdx.x * 32;
  int tid = threadIdx.x;
  int w = tid >> 6, l = tid & 63, l15 = l & 15, lg = l >> 4;

  const float* xb = x + (size_t)(m0 + l15) * 1024 + lg * 8;
  const ushort_t* wp0;
  const ushort_t* wp1;
  const ushort_t* wp2;
  {
    int cg0 = w * 3, cg1 = w * 3 + 1, cg2 = w * 3 + 2;
    wp0 = Wt + (cg0 >> 3) * 131072 + ((cg0 & 7) * 16 + l15) * 1024 + lg * 8;
    wp1 = Wt + (cg1 >> 3) * 131072 + ((cg1 & 7) * 16 + l15) * 1024 + lg * 8;
    wp2 = Wt + (cg2 >> 3) * 131072 + ((cg2 & 7) * 16 + l15) * 1024 + lg * 8;
  }
  f32x4 acc[3][2];
#pragma unroll
  for (int g = 0; g < 3; ++g)
#pragma unroll
    for (int h = 0; h < 2; ++h) acc[g][h] = (f32x4){0.f, 0.f, 0.f, 0.f};

#pragma unroll 4
  for (int kc = 0; kc < 32; ++kc) {
    float4 a00 = *(const float4*)(xb + kc * 32);
    float4 a01 = *(const float4*)(xb + kc * 32 + 4);
    float4 a10 = *(const float4*)(xb + kc * 32 + 16384);
    float4 a11 = *(const float4*)(xb + kc * 32 + 16388);
    short8 b0 = *(const short8*)(wp0 + kc * 32);
    short8 b1 = *(const short8*)(wp1 + kc * 32);
    short8 b2 = *(const short8*)(wp2 + kc * 32);
    short8 a0 = pack8(a00, a01);
    short8 a1 = pack8(a10, a11);
    acc[0][0] = __builtin_amdgcn_mfma_f32_16x16x32_bf16(a0, b0, acc[0][0], 0, 0, 0);
    acc[0][1] = __builtin_amdgcn_mfma_f32_16x16x32_bf16(a1, b0, acc[0][1], 0, 0, 0);
    acc[1][0] = __builtin_amdgcn_mfma_f32_16x16x32_bf16(a0, b1, acc[1][0], 0, 0, 0);
    acc[1][1] = __builtin_amdgcn_mfma_f32_16x16x32_bf16(a1, b1, acc[1][1], 0, 0, 0);
    acc[2][0] = __builtin_amdgcn_mfma_f32_16x16x32_bf16(a0, b2, acc[2][0], 0, 0, 0);
    acc[2][1] = __builtin_amdgcn_mfma_f32_16x16x32_bf16(a1, b2, acc[2][1], 0, 0, 0);
  }

#pragma unroll
  for (int g = 0; g < 3; ++g) {
    int cg = w * 3 + g;
    int o = cg >> 3;
    int col = (cg & 7) * 16 + l15;
#pragma unroll
    for (int h = 0; h < 2; ++h)
#pragma unroll
      for (int j = 0; j < 4; ++j) {
        int row = m0 + h * 16 + lg * 4 + j;
        float vv = acc[g][h][j];
        if (o == 0) {
          qb[(size_t)row * 128 + col] = f2bf(vv * 0.03125f);
        } else if (o == 1) {
          kb[(size_t)row * 128 + col] = f2bf(vv);
        } else {
          vt[((size_t)((row >> 12) * 128 + col)) * 4096 + (row & 4095)] = f2bf(vv);
        }
      }
  }
}

// -------------------- Kernel 2: sliced causal flash attention --------------------
// VERBATIM round-2 version (passing). Strips of 128 q-rows (4 waves x 32 rows).
// kv units of 64 keys; strip s has nt=2s+2 units, ns=(s/4)+1 slices -> 576 blocks.
__global__ __launch_bounds__(256, 2) void attn_slice(const ushort_t* __restrict__ qb,
                                                     const ushort_t* __restrict__ kb,
                                                     const ushort_t* __restrict__ vt,
                                                     ushort_t* __restrict__ pO,
                                                     float* __restrict__ pML) {
  __shared__ __align__(16) ushort_t ldsK[64][128];   // granule g^=r&15
  __shared__ __align__(16) ushort_t ldsV[128][64];   // granule g^=r&7 (V^T)
  __shared__ __align__(16) ushort_t ldsP[4][32][64]; // per-wave P, g^=row&7

  int bid = blockIdx.x;
  int e = 143 - (bid >> 2);  // heavy entries first
  int b = bid & 3;
  int s = 0, j = 0, base = 0;
#pragma unroll
  for (int g = 0; g < 8; ++g) {
    int sz = 4 * (g + 1);
    if (e < base + sz) {
      int r = e - base;
      s = 4 * g + r / (g + 1);
      j = r % (g + 1);
      break;
    }
    base += sz;
  }
  int nt = 2 * s + 2, ns = (s >> 2) + 1;
  int u0 = j * nt / ns, u1 = (j + 1) * nt / ns;

  int tid = threadIdx.x, w = tid >> 6, l = tid & 63, l15 = l & 15, lg = l >> 4;
  int r0w = 128 * s + 32 * w;

  const ushort_t* qp = qb + (size_t)(b * 4096 + r0w + l15) * 128;
  short8 aq[2][4];
#pragma unroll
  for (int h = 0; h < 2; ++h)
#pragma unroll
    for (int c = 0; c < 4; ++c) aq[h][c] = *(const short8*)(qp + h * 2048 + c * 32 + lg * 8);

  f32x4 accO[2][8];
#pragma unroll
  for (int h = 0; h < 2; ++h)
#pragma unroll
    for (int i = 0; i < 8; ++i) accO[h][i] = (f32x4){0.f, 0.f, 0.f, 0.f};
  float m[2][4], lsum[2][4];
#pragma unroll
  for (int h = 0; h < 2; ++h)
#pragma unroll
    for (int jj = 0; jj < 4; ++jj) { m[h][jj] = -1e30f; lsum[h][jj] = 0.f; }

  for (int u = u0; u < u1; ++u) {
    {  // stage K tile [64 keys][128] + V^T tile [128 d][64]
      const ushort_t* ksrc = kb + ((size_t)b * 4096 + u * 64) * 128;
#pragma unroll
      for (int i = 0; i < 4; ++i) {
        int d = i * 256 + tid;
        int r = d >> 4, g = d & 15;
        uint4 v = *(const uint4*)(ksrc + r * 128 + g * 8);
        *(uint4*)&ldsK[r][(g ^ (r & 15)) * 8] = v;
      }
      const ushort_t* vsrc = vt + (size_t)b * 524288 + u * 64;
#pragma unroll
      for (int i = 0; i < 4; ++i) {
        int d = i * 256 + tid;
        int r = d >> 3, g = d & 7;
        uint4 v = *(const uint4*)(vsrc + (size_t)r * 4096 + g * 8);
        *(uint4*)&ldsV[r][(g ^ (r & 7)) * 8] = v;
      }
    }
    __syncthreads();
    bool skip = (64 * u > r0w + 31);
    if (!skip) {
      f32x4 s_[2][4];
#pragma unroll
      for (int h = 0; h < 2; ++h)
#pragma unroll
        for (int fi = 0; fi < 4; ++fi) s_[h][fi] = (f32x4){0.f, 0.f, 0.f, 0.f};
#pragma unroll
      for (int c = 0; c < 4; ++c)
#pragma unroll
        for (int fi = 0; fi < 4; ++fi) {
          short8 bk = *(const short8*)&ldsK[fi * 16 + l15][((c * 4 + lg) ^ l15) * 8];
          s_[0][fi] = __builtin_amdgcn_mfma_f32_16x16x32_bf16(aq[0][c], bk, s_[0][fi], 0, 0, 0);
          s_[1][fi] = __builtin_amdgcn_mfma_f32_16x16x32_bf16(aq[1][c], bk, s_[1][fi], 0, 0, 0);
        }
      if (64 * u + 63 > r0w) {
#pragma unroll
        for (int h = 0; h < 2; ++h)
#pragma unroll
          for (int fi = 0; fi < 4; ++fi) {
            int key = 64 * u + fi * 16 + l15;
#pragma unroll
            for (int jj = 0; jj < 4; ++jj)
              if (key > r0w + h * 16 + lg * 4 + jj) s_[h][fi][jj] = -__builtin_inff();
          }
      }
      float tm[2][4];
#pragma unroll
      for (int h = 0; h < 2; ++h)
#pragma unroll
        for (int jj = 0; jj < 4; ++jj)
          tm[h][jj] = fmaxf(fmaxf(s_[h][0][jj], s_[h][1][jj]), fmaxf(s_[h][2][jj], s_[h][3][jj]));
#pragma unroll
      for (int d = 1; d < 16; d <<= 1)
#pragma unroll
        for (int h = 0; h < 2; ++h)
#pragma unroll
          for (int jj = 0; jj < 4; ++jj) tm[h][jj] = fmaxf(tm[h][jj], __shfl_xor(tm[h][jj], d));
      float sc[2][4], rs[2][4], mn[2][4];
#pragma unroll
      for (int h = 0; h < 2; ++h)
#pragma unroll
        for (int jj = 0; jj < 4; ++jj) {
          mn[h][jj] = fmaxf(m[h][jj], tm[h][jj]);
          sc[h][jj] = __expf(m[h][jj] - mn[h][jj]);
          rs[h][jj] = 0.f;
        }
#pragma unroll
      for (int h = 0; h < 2; ++h)
#pragma unroll
        for (int fi = 0; fi < 4; ++fi)
#pragma unroll
          for (int jj = 0; jj < 4; ++jj) {
            float p = __expf(s_[h][fi][jj] - mn[h][jj]);
            s_[h][fi][jj] = p;
            rs[h][jj] += p;
          }
#pragma unroll
      for (int d = 1; d < 16; d <<= 1)
#pragma unroll
        for (int h = 0; h < 2; ++h)
#pragma unroll
          for (int jj = 0; jj < 4; ++jj) rs[h][jj] += __shfl_xor(rs[h][jj], d);
#pragma unroll
      for (int h = 0; h < 2; ++h)
#pragma unroll
        for (int jj = 0; jj < 4; ++jj) {
          lsum[h][jj] = lsum[h][jj] * sc[h][jj] + rs[h][jj];
          m[h][jj] = mn[h][jj];
        }
#pragma unroll
      for (int h = 0; h < 2; ++h)
#pragma unroll
        for (int f = 0; f < 8; ++f)
#pragma unroll
          for (int jj = 0; jj < 4; ++jj) accO[h][f][jj] *= sc[h][jj];
#pragma unroll
      for (int h = 0; h < 2; ++h)
#pragma unroll
        for (int fi = 0; fi < 4; ++fi)
#pragma unroll
          for (int jj = 0; jj < 4; ++jj) {
            int row = h * 16 + lg * 4 + jj;
            int gidx = fi * 2 + (l15 >> 3);
            ldsP[w][row][((gidx ^ (row & 7)) << 3) | (l15 & 7)] = f2bf(s_[h][fi][jj]);
          }
      short8 ap[2][2];
#pragma unroll
      for (int h = 0; h < 2; ++h)
#pragma unroll
        for (int c = 0; c < 2; ++c)
          ap[h][c] = *(const short8*)&ldsP[w][h * 16 + l15][((c * 4 + lg) ^ (l15 & 7)) * 8];
#pragma unroll
      for (int c = 0; c < 2; ++c)
#pragma unroll
        for (int f = 0; f < 8; ++f) {
          short8 bv = *(const short8*)&ldsV[f * 16 + l15][((c * 4 + lg) ^ (l15 & 7)) * 8];
          accO[0][f] = __builtin_amdgcn_mfma_f32_16x16x32_bf16(ap[0][c], bv, accO[0][f], 0, 0, 0);
          accO[1][f] = __builtin_amdgcn_mfma_f32_16x16x32_bf16(ap[1][c], bv, accO[1][f], 0, 0, 0);
        }
    }
    __syncthreads();
  }

  size_t obase = (size_t)bid * 16384;
#pragma unroll
  for (int h = 0; h < 2; ++h)
#pragma unroll
    for (int f = 0; f < 8; ++f)
#pragma unroll
      for (int jj = 0; jj < 4; ++jj) {
        int row = w * 32 + h * 16 + lg * 4 + jj;
        pO[obase + (size_t)row * 128 + f * 16 + l15] = f2bf(accO[h][f][jj]);
      }
  if (l15 == 0) {
#pragma unroll
    for (int h = 0; h < 2; ++h)
#pragma unroll
      for (int jj = 0; jj < 4; ++jj) {
        int row = w * 32 + h * 16 + lg * 4 + jj;
        pML[(size_t)bid * 256 + row * 2 + 0] = m[h][jj];
        pML[(size_t)bid * 256 + row * 2 + 1] = lsum[h][jj];
      }
  }
}

// -------------------- Kernel 3: merge split-K partials --------------------
__global__ __launch_bounds__(256) void attn_merge(const ushort_t* __restrict__ pO,
                                                  const float* __restrict__ pML,
                                                  float* __restrict__ out) {
  int idx = blockIdx.x * 256 + threadIdx.x;  // 524288 threads
  int row = idx >> 5;
  int cg = (idx & 31) * 4;
  int b = row >> 12, sr = row & 4095;
  int s = sr >> 7, g = s >> 2, ns = g + 1;
  int cumS = (g + 1) * (s - 2 * g);
  int rr = sr & 127;
  float M = -1e30f;
  for (int j = 0; j < ns; ++j) {
    int gid = (143 - (cumS + j)) * 4 + b;
    M = fmaxf(M, pML[(size_t)gid * 256 + rr * 2 + 0]);
  }
  float L = 0.f;
  float o0 = 0.f, o1 = 0.f, o2 = 0.f, o3 = 0.f;
  for (int j = 0; j < ns; ++j) {
    int gid = (143 - (cumS + j)) * 4 + b;
    float mv = pML[(size_t)gid * 256 + rr * 2 + 0];
    float lv = pML[(size_t)gid * 256 + rr * 2 + 1];
    float coef = __expf(mv - M);
    L += lv * coef;
    const ushort_t* op = pO + (size_t)gid * 16384 + rr * 128 + cg;
    uint2 pv = *(const uint2*)op;
    o0 += coef * bf2f((ushort_t)(pv.x & 0xffff));
    o1 += coef * bf2f((ushort_t)(pv.x >> 16));
    o2 += coef * bf2f((ushort_t)(pv.y & 0xffff));
    o3 += coef * bf2f((ushort_t)(pv.y >> 16));
  }
  float inv = 1.0f / L;
  float4 r = {o0 * inv, o1 * inv, o2 * inv, o3 * inv};
  *(float4*)(out + (size_t)row * 128 + cg) = r;
}

// -------------------- launch --------------------
extern "C" void kernel_launch(void* const* d_in, const int* in_sizes, int n_in,
                              void* d_out, int out_size, void* d_ws, size_t ws_size,
                              hipStream_t stream) {
  const float* x = (const float*)d_in[0];
  const float* Wk = (const float*)d_in[1];
  const float* Wq = (const float*)d_in[2];
  const float* Wv = (const float*)d_in[3];
  float* out = (float*)d_out;
  char* ws = (char*)d_ws;
  ushort_t* Wt = (ushort_t*)(ws);                         // 768 KB
  ushort_t* qb = (ushort_t*)(ws + 786432);                // 4 MB
  ushort_t* kbp = (ushort_t*)(ws + 786432 + 4194304);     // 4 MB
  ushort_t* vt = (ushort_t*)(ws + 786432 + 8388608);      // 4 MB
  ushort_t* pO = (ushort_t*)(ws + 13369344);              // 18.87 MB
  float* pML = (float*)(ws + 32243712);                   // 0.59 MB

  hipLaunchKernelGGL(wt_prep, dim3(1536), dim3(256), 0, stream, Wq, Wk, Wv, Wt);
  hipLaunchKernelGGL(proj, dim3(512), dim3(512), 0, stream, x, Wt, qb, kbp, vt);
  hipLaunchKernelGGL(attn_slice, dim3(576), dim3(256), 0, stream, qb, kbp, vt, pO, pML);
  hipLaunchKernelGGL(attn_merge, dim3(2048), dim3(256), 0, stream, pO, pML, out);
}

// Round 5
// 192.660 us; speedup vs baseline: 1.3236x; 1.3236x over previous
//
#include <hip/hip_runtime.h>

typedef __attribute__((ext_vector_type(8))) short short8;
typedef __attribute__((ext_vector_type(4))) float f32x4;
typedef unsigned short ushort_t;
typedef unsigned int uint_t;

#define SEQ 4096
#define NB 4
#define EMB 1024
#define HD 128

__device__ __forceinline__ ushort_t f2bf(float f) {
  uint_t u = __float_as_uint(f);
  u += 0x7fffu + ((u >> 16) & 1u);
  return (ushort_t)(u >> 16);
}
__device__ __forceinline__ float bf2f(ushort_t h) {
  return __uint_as_float(((uint_t)h) << 16);
}

// -------------------- Kernel 0: weight prep --------------------
// Wt2 layout: [kc 16][n 384][64 k-els], K-panelized AND pre-swizzled:
// within row n, physical granule p (16B = 8 els) holds logical granule
// g = p ^ (n&7), logical k = kc*64 + g*8 + e. n = o*128 + nn (o: 0=q,1=k,2=v).
// proj then stages B with a straight contiguous copy into linear LDS and
// reads fragments with the same XOR -> conflict-free, correct (rule 21).
__global__ __launch_bounds__(256) void wt_prep(const float* __restrict__ Wq,
                                               const float* __restrict__ Wk,
                                               const float* __restrict__ Wv,
                                               ushort_t* __restrict__ Wt2) {
  int idx = blockIdx.x * 256 + threadIdx.x;  // [0, 393216)
  int kc = idx / 24576;
  int rem = idx - kc * 24576;
  int n = rem >> 6;
  int p = (rem >> 3) & 7;
  int e = rem & 7;
  int g = p ^ (n & 7);
  int k = kc * 64 + g * 8 + e;
  int o = n >> 7, nn = n & 127;
  const float* W = (o == 0) ? Wq : ((o == 1) ? Wk : Wv);
  Wt2[idx] = f2bf(W[k * 128 + nn]);
}

// -------------------- Kernel 1: fused QKV projection (LDS-staged GEMM) ------
// 512 blocks x 512 thr (8 waves), 2 blocks/CU. Block = 32 x-rows, all 384 cols.
// BK=64 (16 K-steps). All GLOBAL accesses coalesced; fragment scatter via LDS.
// Wave w owns cols [w*48, w*48+48): 2 M-frags x 3 N-frags, acc = 24 VGPR.
__global__ __launch_bounds__(512, 4) void proj(const float* __restrict__ x,
                                               const ushort_t* __restrict__ Wt2,
                                               ushort_t* __restrict__ qb,
                                               ushort_t* __restrict__ kb,
                                               ushort_t* __restrict__ vt) {
  __shared__ __align__(16) ushort_t ldsA[32 * 64];   // 4 KB, XOR-swizzled granules
  __shared__ __align__(16) ushort_t ldsB[384 * 64];  // 48 KB, linear (pre-swizzled in Wt2)
  int m0 = blockIdx.x * 32;
  int tid = threadIdx.x;
  int w = tid >> 6, l = tid & 63, l15 = l & 15, lg = l >> 4;

  f32x4 acc[2][3];
#pragma unroll
  for (int mf = 0; mf < 2; ++mf)
#pragma unroll
    for (int f = 0; f < 3; ++f) acc[mf][f] = (f32x4){0.f, 0.f, 0.f, 0.f};

  // A staging map: thread t -> row = t>>4, 4 fp32 els at k4 = (t&15)*4.
  // Wave-inst = 4 contiguous 256B segments. Swizzled dest (granule ^ row&7).
  int arow = tid >> 4;
  int asub = tid & 15;
  const float* xsrc = x + (size_t)(m0 + arow) * 1024 + asub * 4;
  ushort_t* adst = ldsA + arow * 64 + ((((asub >> 1) ^ (arow & 7)) << 3) | ((asub & 1) << 2));

  for (int kc = 0; kc < 16; ++kc) {
    // stage A (fp32 -> bf16, once per element)
    float4 xa = *(const float4*)(xsrc + kc * 64);
    uint2 aw;
    aw.x = (uint_t)f2bf(xa.x) | ((uint_t)f2bf(xa.y) << 16);
    aw.y = (uint_t)f2bf(xa.z) | ((uint_t)f2bf(xa.w) << 16);
    *(uint2*)adst = aw;
    // stage B: contiguous 48 KB panel -> linear LDS (6 x 16B per thread)
    const ushort_t* bsrc = Wt2 + kc * 24576;
#pragma unroll
    for (int j2 = 0; j2 < 6; ++j2) {
      int u = j2 * 512 + tid;
      *(uint4*)(ldsB + u * 8) = *(const uint4*)(bsrc + u * 8);
    }
    __syncthreads();
#pragma unroll
    for (int c = 0; c < 2; ++c) {
      int g = c * 4 + lg;
      short8 af[2];
#pragma unroll
      for (int mf = 0; mf < 2; ++mf) {
        int r = mf * 16 + l15;
        af[mf] = *(const short8*)(ldsA + r * 64 + ((g ^ (r & 7)) << 3));
      }
#pragma unroll
      for (int f = 0; f < 3; ++f) {
        int n = w * 48 + f * 16 + l15;
        short8 bf = *(const short8*)(ldsB + n * 64 + ((g ^ (n & 7)) << 3));
        acc[0][f] = __builtin_amdgcn_mfma_f32_16x16x32_bf16(af[0], bf, acc[0][f], 0, 0, 0);
        acc[1][f] = __builtin_amdgcn_mfma_f32_16x16x32_bf16(af[1], bf, acc[1][f], 0, 0, 0);
      }
    }
    __syncthreads();
  }

  // epilogue: C layout col = l15, row = lg*4 + j
#pragma unroll
  for (int f = 0; f < 3; ++f) {
    int cg = w * 48 + f * 16 + l15;  // [0,384)
    int o = cg >> 7, col = cg & 127;
#pragma unroll
    for (int mf = 0; mf < 2; ++mf)
#pragma unroll
      for (int j = 0; j < 4; ++j) {
        int row = m0 + mf * 16 + lg * 4 + j;
        float vv = acc[mf][f][j];
        if (o == 0) {
          qb[(size_t)row * 128 + col] = f2bf(vv * 0.03125f);
        } else if (o == 1) {
          kb[(size_t)row * 128 + col] = f2bf(vv);
        } else {
          vt[((size_t)((row >> 12) * 128 + col)) * 4096 + (row & 4095)] = f2bf(vv);
        }
      }
  }
}

// -------------------- Kernel 2: sliced causal flash attention --------------------
// VERBATIM round-4 version (passing). Strips of 128 q-rows (4 waves x 32 rows).
// kv units of 64 keys; strip s has nt=2s+2 units, ns=(s/4)+1 slices -> 576 blocks.
__global__ __launch_bounds__(256, 2) void attn_slice(const ushort_t* __restrict__ qb,
                                                     const ushort_t* __restrict__ kb,
                                                     const ushort_t* __restrict__ vt,
                                                     ushort_t* __restrict__ pO,
                                                     float* __restrict__ pML) {
  __shared__ __align__(16) ushort_t ldsK[64][128];   // granule g^=r&15
  __shared__ __align__(16) ushort_t ldsV[128][64];   // granule g^=r&7 (V^T)
  __shared__ __align__(16) ushort_t ldsP[4][32][64]; // per-wave P, g^=row&7

  int bid = blockIdx.x;
  int e = 143 - (bid >> 2);  // heavy entries first
  int b = bid & 3;
  int s = 0, j = 0, base = 0;
#pragma unroll
  for (int g = 0; g < 8; ++g) {
    int sz = 4 * (g + 1);
    if (e < base + sz) {
      int r = e - base;
      s = 4 * g + r / (g + 1);
      j = r % (g + 1);
      break;
    }
    base += sz;
  }
  int nt = 2 * s + 2, ns = (s >> 2) + 1;
  int u0 = j * nt / ns, u1 = (j + 1) * nt / ns;

  int tid = threadIdx.x, w = tid >> 6, l = tid & 63, l15 = l & 15, lg = l >> 4;
  int r0w = 128 * s + 32 * w;

  const ushort_t* qp = qb + (size_t)(b * 4096 + r0w + l15) * 128;
  short8 aq[2][4];
#pragma unroll
  for (int h = 0; h < 2; ++h)
#pragma unroll
    for (int c = 0; c < 4; ++c) aq[h][c] = *(const short8*)(qp + h * 2048 + c * 32 + lg * 8);

  f32x4 accO[2][8];
#pragma unroll
  for (int h = 0; h < 2; ++h)
#pragma unroll
    for (int i = 0; i < 8; ++i) accO[h][i] = (f32x4){0.f, 0.f, 0.f, 0.f};
  float m[2][4], lsum[2][4];
#pragma unroll
  for (int h = 0; h < 2; ++h)
#pragma unroll
    for (int jj = 0; jj < 4; ++jj) { m[h][jj] = -1e30f; lsum[h][jj] = 0.f; }

  for (int u = u0; u < u1; ++u) {
    {  // stage K tile [64 keys][128] + V^T tile [128 d][64]
      const ushort_t* ksrc = kb + ((size_t)b * 4096 + u * 64) * 128;
#pragma unroll
      for (int i = 0; i < 4; ++i) {
        int d = i * 256 + tid;
        int r = d >> 4, g = d & 15;
        uint4 v = *(const uint4*)(ksrc + r * 128 + g * 8);
        *(uint4*)&ldsK[r][(g ^ (r & 15)) * 8] = v;
      }
      const ushort_t* vsrc = vt + (size_t)b * 524288 + u * 64;
#pragma unroll
      for (int i = 0; i < 4; ++i) {
        int d = i * 256 + tid;
        int r = d >> 3, g = d & 7;
        uint4 v = *(const uint4*)(vsrc + (size_t)r * 4096 + g * 8);
        *(uint4*)&ldsV[r][(g ^ (r & 7)) * 8] = v;
      }
    }
    __syncthreads();
    bool skip = (64 * u > r0w + 31);
    if (!skip) {
      f32x4 s_[2][4];
#pragma unroll
      for (int h = 0; h < 2; ++h)
#pragma unroll
        for (int fi = 0; fi < 4; ++fi) s_[h][fi] = (f32x4){0.f, 0.f, 0.f, 0.f};
#pragma unroll
      for (int c = 0; c < 4; ++c)
#pragma unroll
        for (int fi = 0; fi < 4; ++fi) {
          short8 bk = *(const short8*)&ldsK[fi * 16 + l15][((c * 4 + lg) ^ l15) * 8];
          s_[0][fi] = __builtin_amdgcn_mfma_f32_16x16x32_bf16(aq[0][c], bk, s_[0][fi], 0, 0, 0);
          s_[1][fi] = __builtin_amdgcn_mfma_f32_16x16x32_bf16(aq[1][c], bk, s_[1][fi], 0, 0, 0);
        }
      if (64 * u + 63 > r0w) {
#pragma unroll
        for (int h = 0; h < 2; ++h)
#pragma unroll
          for (int fi = 0; fi < 4; ++fi) {
            int key = 64 * u + fi * 16 + l15;
#pragma unroll
            for (int jj = 0; jj < 4; ++jj)
              if (key > r0w + h * 16 + lg * 4 + jj) s_[h][fi][jj] = -__builtin_inff();
          }
      }
      float tm[2][4];
#pragma unroll
      for (int h = 0; h < 2; ++h)
#pragma unroll
        for (int jj = 0; jj < 4; ++jj)
          tm[h][jj] = fmaxf(fmaxf(s_[h][0][jj], s_[h][1][jj]), fmaxf(s_[h][2][jj], s_[h][3][jj]));
#pragma unroll
      for (int d = 1; d < 16; d <<= 1)
#pragma unroll
        for (int h = 0; h < 2; ++h)
#pragma unroll
          for (int jj = 0; jj < 4; ++jj) tm[h][jj] = fmaxf(tm[h][jj], __shfl_xor(tm[h][jj], d));
      float sc[2][4], rs[2][4], mn[2][4];
#pragma unroll
      for (int h = 0; h < 2; ++h)
#pragma unroll
        for (int jj = 0; jj < 4; ++jj) {
          mn[h][jj] = fmaxf(m[h][jj], tm[h][jj]);
          sc[h][jj] = __expf(m[h][jj] - mn[h][jj]);
          rs[h][jj] = 0.f;
        }
#pragma unroll
      for (int h = 0; h < 2; ++h)
#pragma unroll
        for (int fi = 0; fi < 4; ++fi)
#pragma unroll
          for (int jj = 0; jj < 4; ++jj) {
            float p = __expf(s_[h][fi][jj] - mn[h][jj]);
            s_[h][fi][jj] = p;
            rs[h][jj] += p;
          }
#pragma unroll
      for (int d = 1; d < 16; d <<= 1)
#pragma unroll
        for (int h = 0; h < 2; ++h)
#pragma unroll
          for (int jj = 0; jj < 4; ++jj) rs[h][jj] += __shfl_xor(rs[h][jj], d);
#pragma unroll
      for (int h = 0; h < 2; ++h)
#pragma unroll
        for (int jj = 0; jj < 4; ++jj) {
          lsum[h][jj] = lsum[h][jj] * sc[h][jj] + rs[h][jj];
          m[h][jj] = mn[h][jj];
        }
#pragma unroll
      for (int h = 0; h < 2; ++h)
#pragma unroll
        for (int f = 0; f < 8; ++f)
#pragma unroll
          for (int jj = 0; jj < 4; ++jj) accO[h][f][jj] *= sc[h][jj];
#pragma unroll
      for (int h = 0; h < 2; ++h)
#pragma unroll
        for (int fi = 0; fi < 4; ++fi)
#pragma unroll
          for (int jj = 0; jj < 4; ++jj) {
            int row = h * 16 + lg * 4 + jj;
            int gidx = fi * 2 + (l15 >> 3);
            ldsP[w][row][((gidx ^ (row & 7)) << 3) | (l15 & 7)] = f2bf(s_[h][fi][jj]);
          }
      short8 ap[2][2];
#pragma unroll
      for (int h = 0; h < 2; ++h)
#pragma unroll
        for (int c = 0; c < 2; ++c)
          ap[h][c] = *(const short8*)&ldsP[w][h * 16 + l15][((c * 4 + lg) ^ (l15 & 7)) * 8];
#pragma unroll
      for (int c = 0; c < 2; ++c)
#pragma unroll
        for (int f = 0; f < 8; ++f) {
          short8 bv = *(const short8*)&ldsV[f * 16 + l15][((c * 4 + lg) ^ (l15 & 7)) * 8];
          accO[0][f] = __builtin_amdgcn_mfma_f32_16x16x32_bf16(ap[0][c], bv, accO[0][f], 0, 0, 0);
          accO[1][f] = __builtin_amdgcn_mfma_f32_16x16x32_bf16(ap[1][c], bv, accO[1][f], 0, 0, 0);
        }
    }
    __syncthreads();
  }

  size_t obase = (size_t)bid * 16384;
#pragma unroll
  for (int h = 0; h < 2; ++h)
#pragma unroll
    for (int f = 0; f < 8; ++f)
#pragma unroll
      for (int jj = 0; jj < 4; ++jj) {
        int row = w * 32 + h * 16 + lg * 4 + jj;
        pO[obase + (size_t)row * 128 + f * 16 + l15] = f2bf(accO[h][f][jj]);
      }
  if (l15 == 0) {
#pragma unroll
    for (int h = 0; h < 2; ++h)
#pragma unroll
      for (int jj = 0; jj < 4; ++jj) {
        int row = w * 32 + h * 16 + lg * 4 + jj;
        pML[(size_t)bid * 256 + row * 2 + 0] = m[h][jj];
        pML[(size_t)bid * 256 + row * 2 + 1] = lsum[h][jj];
      }
  }
}

// -------------------- Kernel 3: merge split-K partials --------------------
__global__ __launch_bounds__(256) void attn_merge(const ushort_t* __restrict__ pO,
                                                  const float* __restrict__ pML,
                                                  float* __restrict__ out) {
  int idx = blockIdx.x * 256 + threadIdx.x;  // 524288 threads
  int row = idx >> 5;
  int cg = (idx & 31) * 4;
  int b = row >> 12, sr = row & 4095;
  int s = sr >> 7, g = s >> 2, ns = g + 1;
  int cumS = (g + 1) * (s - 2 * g);
  int rr = sr & 127;
  float M = -1e30f;
  for (int j = 0; j < ns; ++j) {
    int gid = (143 - (cumS + j)) * 4 + b;
    M = fmaxf(M, pML[(size_t)gid * 256 + rr * 2 + 0]);
  }
  float L = 0.f;
  float o0 = 0.f, o1 = 0.f, o2 = 0.f, o3 = 0.f;
  for (int j = 0; j < ns; ++j) {
    int gid = (143 - (cumS + j)) * 4 + b;
    float mv = pML[(size_t)gid * 256 + rr * 2 + 0];
    float lv = pML[(size_t)gid * 256 + rr * 2 + 1];
    float coef = __expf(mv - M);
    L += lv * coef;
    const ushort_t* op = pO + (size_t)gid * 16384 + rr * 128 + cg;
    uint2 pv = *(const uint2*)op;
    o0 += coef * bf2f((ushort_t)(pv.x & 0xffff));
    o1 += coef * bf2f((ushort_t)(pv.x >> 16));
    o2 += coef * bf2f((ushort_t)(pv.y & 0xffff));
    o3 += coef * bf2f((ushort_t)(pv.y >> 16));
  }
  float inv = 1.0f / L;
  float4 r = {o0 * inv, o1 * inv, o2 * inv, o3 * inv};
  *(float4*)(out + (size_t)row * 128 + cg) = r;
}

// -------------------- launch --------------------
extern "C" void kernel_launch(void* const* d_in, const int* in_sizes, int n_in,
                              void* d_out, int out_size, void* d_ws, size_t ws_size,
                              hipStream_t stream) {
  const float* x = (const float*)d_in[0];
  const float* Wk = (const float*)d_in[1];
  const float* Wq = (const float*)d_in[2];
  const float* Wv = (const float*)d_in[3];
  float* out = (float*)d_out;
  char* ws = (char*)d_ws;
  ushort_t* Wt2 = (ushort_t*)(ws);                        // 768 KB
  ushort_t* qb = (ushort_t*)(ws + 786432);                // 4 MB
  ushort_t* kbp = (ushort_t*)(ws + 786432 + 4194304);     // 4 MB
  ushort_t* vt = (ushort_t*)(ws + 786432 + 8388608);      // 4 MB
  ushort_t* pO = (ushort_t*)(ws + 13369344);              // 18.87 MB
  float* pML = (float*)(ws + 32243712);                   // 0.59 MB

  hipLaunchKernelGGL(wt_prep, dim3(1536), dim3(256), 0, stream, Wq, Wk, Wv, Wt2);
  hipLaunchKernelGGL(proj, dim3(512), dim3(512), 0, stream, x, Wt2, qb, kbp, vt);
  hipLaunchKernelGGL(attn_slice, dim3(576), dim3(256), 0, stream, qb, kbp, vt, pO, pML);
  hipLaunchKernelGGL(attn_merge, dim3(2048), dim3(256), 0, stream, pO, pML, out);
}